// Round 6
// baseline (709.164 us; speedup 1.0000x reference)
//
#include <hip/hip_runtime.h>
#include <hip/hip_bf16.h>

// Problem constants
#define NS 2560      // B*N sentences
#define NT 70        // tokens per sentence
#define NH 200       // hidden
#define NHP 208      // padded h row stride
#define NI 60        // input dim (50 + 5 + 5)
#define NREL 100
#define NBAG 128
#define NPB 20       // sentences per bag

#define NTRI 13      // gate triples of 16 (13*16 = 208 >= 200)
#define FRAG 512     // bytes per fp8 B fragment (64 lanes x 8)

// Packed weight layout per dir:
//  h-part: [tri][pair p2 (10)][lane][16B] + [tri][tail][lane][8B]  = 10,752 B/tri
//          (pairs interleave frag f=2*p2 and f=2*p2+1 at 16B/lane for b128 reads;
//           frag f = kt*3+seg, kt in [0,7) h-ktile, seg in {r,z,n})
//  x-part: [tri][kt2 (2)][seg (3)][512]
#define WPK_H_BYTES (NTRI * 21 * FRAG)        // 139,776
#define WPK_X_BYTES (NTRI * 6 * FRAG)         //  39,936
#define WPK_DIR_BYTES (WPK_H_BYTES + WPK_X_BYTES)
#define GRU_LDS_BYTES (WPK_H_BYTES + 2 * 7 * 32 * 40)   // 157,696

#define PREP_TOTAL (2 * WPK_DIR_BYTES)
#define PREP_BLKS ((PREP_TOTAL + 255) / 256)            // 1404
#define GATH_TOTAL (NT * NS * 15)
#define GATH_BLKS ((GATH_TOTAL + 255) / 256)            // 10500

typedef unsigned short ushort_t;
typedef unsigned char uchar_t;
typedef __attribute__((ext_vector_type(4))) float f32x4;
typedef int v2i __attribute__((ext_vector_type(2), aligned(4)));
typedef unsigned int v4u __attribute__((ext_vector_type(4), aligned(16)));
typedef long v2l __attribute__((ext_vector_type(2), aligned(16)));

__device__ __forceinline__ float sigf(float x) { return 1.0f / (1.0f + __expf(-x)); }
__device__ __forceinline__ float tanh_fast(float x) {
    float e = __expf(2.0f * x);
    return 1.0f - 2.0f / (e + 1.0f);
}
__device__ __forceinline__ ushort_t f2b(float f) {
    __hip_bfloat16 h = __float2bfloat16(f);
    return *(ushort_t*)&h;
}
__device__ __forceinline__ float b2f(ushort_t u) {
    __hip_bfloat16 h = *(__hip_bfloat16*)&u;
    return __bfloat162float(h);
}

// fp8 e4m3 (OCP on gfx950) encode, RTNE
__device__ __forceinline__ uchar_t f2fp8(float f) {
#if __has_builtin(__builtin_amdgcn_cvt_pk_fp8_f32)
    int p = __builtin_amdgcn_cvt_pk_fp8_f32(f, f, 0, false);
    return (uchar_t)(p & 0xff);
#else
    unsigned u = __float_as_uint(f);
    unsigned s = (u >> 24) & 0x80u;
    float a = fabsf(f);
    if (a >= 448.0f) return (uchar_t)(s | 0x7E);
    if (a < 0.015625f) {
        int q = (int)rintf(a * 512.0f);
        return (uchar_t)(s | (unsigned)q);
    }
    unsigned au = __float_as_uint(a);
    int e = (int)(au >> 23) - 127;
    unsigned m = au & 0x7fffffu;
    unsigned keep = m >> 20;
    unsigned rnd = (m >> 19) & 1u;
    unsigned sticky = (m & 0x7ffffu) ? 1u : 0u;
    keep += (rnd & (sticky | (keep & 1u)));
    int ee = e + 7;
    if (keep == 8u) { keep = 0u; ee += 1; }
    if (ee >= 16) return (uchar_t)(s | 0x7E);
    return (uchar_t)(s | ((unsigned)ee << 3) | keep);
#endif
}

__device__ __forceinline__ long ld_long_a4(const void* p) {
    v2i v = *(const v2i*)p;
    long r; __builtin_memcpy(&r, &v, 8); return r;
}

// ---------------------------------------------------------------------------
// Fused: weight pack (blocks [0, PREP_BLKS)) + x gather (rest).
// ---------------------------------------------------------------------------
__global__ void prep_gather_kernel(const float* __restrict__ WihF, const float* __restrict__ WhhF,
                                   const float* __restrict__ WihB, const float* __restrict__ WhhB,
                                   uchar_t* __restrict__ Wpk,
                                   const int* __restrict__ tok, const int* __restrict__ p1,
                                   const int* __restrict__ p2, const float* __restrict__ emb,
                                   const float* __restrict__ pemb, uchar_t* __restrict__ x) {
    if (blockIdx.x < PREP_BLKS) {
        int idx = blockIdx.x * 256 + threadIdx.x;
        if (idx >= PREP_TOTAL) return;
        int d = idx / WPK_DIR_BYTES;
        int r = idx - d * WPK_DIR_BYTES;
        const float* Wih = d ? WihB : WihF;
        const float* Whh = d ? WhhB : WhhF;
        int tri, ktg, seg, ln, j;
        if (r < WPK_H_BYTES) {
            tri = r / 10752;
            int r2 = r % 10752;
            int f;
            if (r2 < 10240) {
                int p2i = r2 >> 10;          // pair index 0..9
                int w16 = r2 & 1023;
                ln = w16 >> 4;
                int b = w16 & 15;
                f = p2i * 2 + (b >> 3);
                j = b & 7;
            } else {
                f = 20;
                int rr = r2 - 10240;
                ln = rr >> 3;
                j = rr & 7;
            }
            ktg = 2 + f / 3;
            seg = f % 3;
        } else {
            int r2 = r - WPK_H_BYTES;
            tri = r2 / 3072;
            int r3 = r2 % 3072;
            ktg = r3 / 1536;
            seg = (r3 % 1536) / 512;
            int e = r3 % 512;
            j = e & 7;
            ln = e >> 3;
        }
        int gl = 16 * tri + (ln & 15);
        int kk = ((ln >> 4) << 3) + j;
        float v = 0.0f;
        if (gl < NH) {
            int g = seg * NH + gl;
            if (ktg < 2) {
                int kx = ktg * 32 + kk;
                if (kx < NI) v = Wih[g * NI + kx];
            } else {
                int kh = (ktg - 2) * 32 + kk;
                if (kh < NH) v = Whh[g * NH + kh];
            }
        }
        Wpk[idx] = f2fp8(v);
    } else {
        int idx = (blockIdx.x - PREP_BLKS) * 256 + threadIdx.x;
        if (idx >= GATH_TOTAL) return;
        int chunk = idx % 15;
        int st = idx / 15;
        int s = st % NS;
        int t = st / NS;
        int o = s * NT + t;
        int d4 = chunk * 4;
        unsigned out = 0;
        #pragma unroll
        for (int e = 0; e < 4; e++) {
            int dd = d4 + e;
            float v;
            if (dd < 50)      v = emb[(long)tok[o] * 50 + dd];
            else if (dd < 55) v = pemb[p1[o] * 5 + (dd - 50)];
            else              v = pemb[p2[o] * 5 + (dd - 55)];
            out |= ((unsigned)f2fp8(v)) << (8 * e);
        }
        *(unsigned*)(x + ((long)t * NS + s) * NI + d4) = out;
    }
}

// ---------------------------------------------------------------------------
// MFMA GRU. 256 blocks (128 groups x 2 dirs), 832 threads = 13 waves.
// Wave w owns gate-triple w (gates [16w,16w+16) of r,z,n). Bh in LDS (loaded
// once), Bx (6 frags) in regs. A: x from global via running lane pointer with
// imm offsets; h in LDS fp8 double-buffer, addresses = step-toggled base + imm.
// One barrier/step. h stores via running pointer + imm, layout [t][s][NHP] bf16.
// ---------------------------------------------------------------------------
__global__ __launch_bounds__(832, 4)
void gru_kernel(const uchar_t* __restrict__ x, const uchar_t* __restrict__ Wpk,
                const float* __restrict__ bihF, const float* __restrict__ bhhF,
                const float* __restrict__ bihB, const float* __restrict__ bhhB,
                ushort_t* __restrict__ hfo, ushort_t* __restrict__ hbo) {
    extern __shared__ __align__(16) uchar_t smem[];
    uchar_t* Bh = smem;                       // [13][10752] paired fp8 B-frags
    uchar_t* AhB = smem + WPK_H_BYTES;        // [2][7][32][40] fp8 A(h) dbuf

    const int dir = blockIdx.x >> 7;
    const int s0 = (blockIdx.x & 127) * NPB;
    const int tid = threadIdx.x;
    const int wv = tid >> 6, ln = tid & 63;
    const int c = ln & 15, quad = ln >> 4;
    const int jl = 16 * wv + c;
    const bool jv = jl < NH;

    const float* bih = dir ? bihB : bihF;
    const float* bhh = dir ? bhhB : bhhF;
    const uchar_t* wdir = Wpk + (long)dir * WPK_DIR_BYTES;
    ushort_t* hd = dir ? hbo : hfo;

    const float br  = jv ? bih[jl] + bhh[jl] : 0.0f;
    const float bz  = jv ? bih[NH + jl] + bhh[NH + jl] : 0.0f;
    const float bnx = jv ? bih[2 * NH + jl] : 0.0f;
    const float bnh = jv ? bhh[2 * NH + jl] : 0.0f;

    // x-part B fragments in registers: i = kt2*3 + seg
    long Bx[6];
    {
        const uchar_t* wx = wdir + WPK_H_BYTES + wv * 3072 + ln * 8;
        #pragma unroll
        for (int i = 0; i < 6; i++) Bx[i] = *(const long*)(wx + i * FRAG);
    }

    // bulk-copy h-part B into LDS (16-B chunks, coalesced)
    {
        const v4u* src = (const v4u*)wdir;
        v4u* dst = (v4u*)Bh;
        for (int i = tid; i < WPK_H_BYTES / 16; i += 832) dst[i] = src[i];
    }
    // zero Ah (h0 = 0; padding stays zero forever)
    for (int i = tid; i < 2 * 7 * 32 * 40 / 4; i += 832) ((unsigned*)AhB)[i] = 0u;
    __syncthreads();

    // loop-invariant bases
    const uchar_t* bt16 = Bh + wv * 10752 + ln * 16;     // paired frags
    const uchar_t* bt8  = Bh + wv * 10752 + 10240 + ln * 8;  // tail frag 20
    const int roff0 = c * 40 + quad * 8;                 // A row c
    const int roff1 = roff0 + 640;                       // A row 16+c
    const int wroff = (jl >> 5) * 1280 + quad * 160 + (jl & 31);
    unsigned aho = 0;                                    // read-phase toggle

    const int tt0 = dir ? (NT - 1) : 0;
    const long xstep = dir ? -(long)(NS * NI) : (long)(NS * NI);
    const long hstep = dir ? -(long)(NS * NHP) : (long)(NS * NHP);
    const uchar_t* xl = x + ((long)tt0 * NS + s0) * NI + c * NI + quad * 8;
    ushort_t* hst = hd + (long)tt0 * NS * NHP + (long)(s0 + quad * 4) * NHP + jl;

    float hold[2][4] = {};   // [mt][reg]

    for (int t = 0; t < NT; t++) {
        // x A-fragments (imm offsets off running lane pointer)
        long ax00 = ld_long_a4(xl);
        long ax01 = ld_long_a4(xl + 32);
        long ax10 = ld_long_a4(xl + 960);
        long ax11 = ld_long_a4(xl + 992);

        // B h-part: 10 paired b128 + 1 b64 (loop-invariant data, no barrier dep)
        long Bv[21];
        #pragma unroll
        for (int p = 0; p < 10; p++) {
            v2l q = *(const v2l*)(bt16 + p * 1024);
            Bv[2 * p] = q.x;
            Bv[2 * p + 1] = q.y;
        }
        Bv[20] = *(const long*)bt8;

        f32x4 aR[2], aZ[2], aNX[2], aNH[2];
        const f32x4 vz = {0.0f, 0.0f, 0.0f, 0.0f};
        aR[0] = aR[1] = aZ[0] = aZ[1] = vz;
        aNX[0] = aNX[1] = aNH[0] = aNH[1] = vz;

        // x contribution (kt2 0,1) — B from registers
        aR[0]  = __builtin_amdgcn_mfma_f32_16x16x32_fp8_fp8(ax00, Bx[0], aR[0], 0, 0, 0);
        aR[1]  = __builtin_amdgcn_mfma_f32_16x16x32_fp8_fp8(ax10, Bx[0], aR[1], 0, 0, 0);
        aZ[0]  = __builtin_amdgcn_mfma_f32_16x16x32_fp8_fp8(ax00, Bx[1], aZ[0], 0, 0, 0);
        aZ[1]  = __builtin_amdgcn_mfma_f32_16x16x32_fp8_fp8(ax10, Bx[1], aZ[1], 0, 0, 0);
        aNX[0] = __builtin_amdgcn_mfma_f32_16x16x32_fp8_fp8(ax00, Bx[2], aNX[0], 0, 0, 0);
        aNX[1] = __builtin_amdgcn_mfma_f32_16x16x32_fp8_fp8(ax10, Bx[2], aNX[1], 0, 0, 0);
        aR[0]  = __builtin_amdgcn_mfma_f32_16x16x32_fp8_fp8(ax01, Bx[3], aR[0], 0, 0, 0);
        aR[1]  = __builtin_amdgcn_mfma_f32_16x16x32_fp8_fp8(ax11, Bx[3], aR[1], 0, 0, 0);
        aZ[0]  = __builtin_amdgcn_mfma_f32_16x16x32_fp8_fp8(ax01, Bx[4], aZ[0], 0, 0, 0);
        aZ[1]  = __builtin_amdgcn_mfma_f32_16x16x32_fp8_fp8(ax11, Bx[4], aZ[1], 0, 0, 0);
        aNX[0] = __builtin_amdgcn_mfma_f32_16x16x32_fp8_fp8(ax01, Bx[5], aNX[0], 0, 0, 0);
        aNX[1] = __builtin_amdgcn_mfma_f32_16x16x32_fp8_fp8(ax11, Bx[5], aNX[1], 0, 0, 0);

        // h contribution (kt 0..6): A from toggled LDS base + imm
        const uchar_t* ar0 = AhB + aho + roff0;
        const uchar_t* ar1 = AhB + aho + roff1;
        #pragma unroll
        for (int kt = 0; kt < 7; kt++) {
            long ah0 = *(const long*)(ar0 + kt * 1280);
            long ah1 = *(const long*)(ar1 + kt * 1280);
            long bR = Bv[kt * 3 + 0];
            long bZ = Bv[kt * 3 + 1];
            long bN = Bv[kt * 3 + 2];
            aR[0]  = __builtin_amdgcn_mfma_f32_16x16x32_fp8_fp8(ah0, bR, aR[0], 0, 0, 0);
            aR[1]  = __builtin_amdgcn_mfma_f32_16x16x32_fp8_fp8(ah1, bR, aR[1], 0, 0, 0);
            aZ[0]  = __builtin_amdgcn_mfma_f32_16x16x32_fp8_fp8(ah0, bZ, aZ[0], 0, 0, 0);
            aZ[1]  = __builtin_amdgcn_mfma_f32_16x16x32_fp8_fp8(ah1, bZ, aZ[1], 0, 0, 0);
            aNH[0] = __builtin_amdgcn_mfma_f32_16x16x32_fp8_fp8(ah0, bN, aNH[0], 0, 0, 0);
            aNH[1] = __builtin_amdgcn_mfma_f32_16x16x32_fp8_fp8(ah1, bN, aNH[1], 0, 0, 0);
        }

        // epilogue; C/D layout: row = quad*4+reg, col = c
        uchar_t* awr = AhB + (aho ^ 8960) + wroff;
        // mt0: rows quad*4+reg (0..15) all real
        #pragma unroll
        for (int reg = 0; reg < 4; reg++) {
            float r = sigf(aR[0][reg] + br);
            float z = sigf(aZ[0][reg] + bz);
            float n = tanh_fast(aNX[0][reg] + bnx + r * (aNH[0][reg] + bnh));
            float hn = (1.0f - z) * n + z * hold[0][reg];
            hold[0][reg] = hn;
            if (jv) {
                awr[reg * 40] = f2fp8(hn);
                hst[reg * NHP] = f2b(hn);
            }
        }
        // mt1: rows 16+quad*4+reg — real only for quad==0 (16..19)
        if (quad == 0) {
            ushort_t* hst1 = hst + 16 * NHP;
            #pragma unroll
            for (int reg = 0; reg < 4; reg++) {
                float r = sigf(aR[1][reg] + br);
                float z = sigf(aZ[1][reg] + bz);
                float n = tanh_fast(aNX[1][reg] + bnx + r * (aNH[1][reg] + bnh));
                float hn = (1.0f - z) * n + z * hold[1][reg];
                hold[1][reg] = hn;
                if (jv) {
                    awr[(16 + reg) * 40] = f2fp8(hn);
                    hst1[reg * NHP] = f2b(hn);
                }
            }
        }

        aho ^= 8960;
        xl += xstep;
        hst += hstep;
        __syncthreads();
    }
}

// ---------------------------------------------------------------------------
// Word-level attention: one block (512 thr) per sentence. h is [t][s][NHP] bf16.
// ---------------------------------------------------------------------------
__global__ __launch_bounds__(512)
void attn_kernel(const ushort_t* __restrict__ hf, const ushort_t* __restrict__ hb,
                 const float* __restrict__ aw, float* __restrict__ H) {
    int s = blockIdx.x;
    int tid = threadIdx.x;
    __shared__ __align__(16) float tup[NT][NHP];
    __shared__ float sc[NT];
    __shared__ float inv_s;
    // stage hf+hb with b128 loads (rows are 16B-aligned: 416 B apart)
    typedef __attribute__((ext_vector_type(8))) short s8;
    for (int i = tid; i < NT * 26; i += 512) {
        int t = i / 26, j8 = (i - t * 26) * 8;
        long off = ((long)t * NS + s) * NHP + j8;
        s8 uf = *(const s8*)(hf + off);
        s8 ub = *(const s8*)(hb + off);
        #pragma unroll
        for (int e = 0; e < 8; e++)
            tup[t][j8 + e] = b2f((ushort_t)uf[e]) + b2f((ushort_t)ub[e]);
    }
    __syncthreads();
    int wvv = tid >> 6, lnn = tid & 63;
    for (int t = wvv; t < NT; t += 8) {
        float p = 0.0f;
        for (int j = lnn; j < NH; j += 64) p += tanh_fast(tup[t][j]) * aw[j];
        #pragma unroll
        for (int off = 32; off > 0; off >>= 1) p += __shfl_down(p, off, 64);
        if (lnn == 0) sc[t] = p;
    }
    __syncthreads();
    if (tid < 64) {
        float v0 = sc[tid < NT ? tid : 0];
        if (tid >= NT) v0 = -1e30f;
        float v1 = (tid + 64 < NT) ? sc[tid + 64] : -1e30f;
        float mx = fmaxf(v0, v1);
        #pragma unroll
        for (int off = 32; off > 0; off >>= 1) mx = fmaxf(mx, __shfl_xor(mx, off, 64));
        float e0 = (tid < NT) ? __expf(v0 - mx) : 0.0f;
        float e1 = (tid + 64 < NT) ? __expf(v1 - mx) : 0.0f;
        float ssum = e0 + e1;
        #pragma unroll
        for (int off = 32; off > 0; off >>= 1) ssum += __shfl_xor(ssum, off, 64);
        if (tid < NT) sc[tid] = e0;
        if (tid + 64 < NT) sc[tid + 64] = e1;
        if (tid == 0) inv_s = 1.0f / ssum;
    }
    __syncthreads();
    float inv = inv_s;
    for (int j = tid; j < NH; j += 512) {
        float acc = 0.0f;
        #pragma unroll 7
        for (int t = 0; t < NT; t++) acc += sc[t] * tup[t][j];
        H[s * NH + j] = acc * inv;
    }
}

// ---------------------------------------------------------------------------
// Bag attention + logits + BCE loss.
// ---------------------------------------------------------------------------
__global__ __launch_bounds__(256)
void bag_kernel(const float* __restrict__ H, const int* __restrict__ label,
                const float* __restrict__ sen_a, const float* __restrict__ sen_r,
                const float* __restrict__ rel, const float* __restrict__ sen_d,
                float* __restrict__ out) {
    int b = blockIdx.x;
    int tid = threadIdx.x;
    __shared__ __align__(16) float Hs[NPB][NH];
    __shared__ float e[NPB];
    __shared__ float Sv[NH];
    __shared__ float part[4];
    const float* Hb = H + b * NPB * NH;
    for (int i = tid; i < NPB * NH; i += 256) (&Hs[0][0])[i] = Hb[i];
    __syncthreads();
    int wvv = tid >> 6, lnn = tid & 63;
    for (int n = wvv; n < NPB; n += 4) {
        float p = 0.0f;
        for (int j = lnn; j < NH; j += 64) p += Hs[n][j] * sen_a[j] * sen_r[j];
        #pragma unroll
        for (int off = 32; off > 0; off >>= 1) p += __shfl_down(p, off, 64);
        if (lnn == 0) e[n] = p;
    }
    __syncthreads();
    if (tid == 0) {
        float mx = e[0];
        for (int n = 1; n < NPB; n++) mx = fmaxf(mx, e[n]);
        float sum = 0.0f;
        for (int n = 0; n < NPB; n++) { float v = __expf(e[n] - mx); e[n] = v; sum += v; }
        float inv = 1.0f / sum;
        for (int n = 0; n < NPB; n++) e[n] *= inv;
    }
    __syncthreads();
    for (int j = tid; j < NH; j += 256) {
        float acc = 0.0f;
        #pragma unroll
        for (int n = 0; n < NPB; n++) acc += e[n] * Hs[n][j];
        Sv[j] = acc;
    }
    __syncthreads();
    float bce = 0.0f;
    if (tid < NREL) {
        float acc = 0.0f;
        #pragma unroll 4
        for (int j = 0; j < NH; j++) acc += Sv[j] * rel[tid * NH + j];
        float l = acc + sen_d[tid];
        out[1 + b * NREL + tid] = l;
        float tgt = (label[b] == tid) ? 1.0f : 0.0f;
        bce = fmaxf(l, 0.0f) - l * tgt + log1pf(__expf(-fabsf(l)));
    }
    #pragma unroll
    for (int off = 32; off > 0; off >>= 1) bce += __shfl_down(bce, off, 64);
    if (lnn == 0) part[wvv] = bce;
    __syncthreads();
    if (tid == 0) {
        float tot = (part[0] + part[1] + part[2] + part[3]) * (1.0f / NREL);
        atomicAdd(out, tot);
    }
}

// ---------------------------------------------------------------------------
extern "C" void kernel_launch(void* const* d_in, const int* in_sizes, int n_in,
                              void* d_out, int out_size, void* d_ws, size_t ws_size,
                              hipStream_t stream) {
    const int*   tok   = (const int*)d_in[0];
    const int*   p1    = (const int*)d_in[1];
    const int*   p2    = (const int*)d_in[2];
    const int*   label = (const int*)d_in[3];
    const float* emb   = (const float*)d_in[4];
    const float* pemb  = (const float*)d_in[5];
    const float* WihF  = (const float*)d_in[6];
    const float* WhhF  = (const float*)d_in[7];
    const float* bihF  = (const float*)d_in[8];
    const float* bhhF  = (const float*)d_in[9];
    const float* WihB  = (const float*)d_in[10];
    const float* WhhB  = (const float*)d_in[11];
    const float* bihB  = (const float*)d_in[12];
    const float* bhhB  = (const float*)d_in[13];
    const float* aw    = (const float*)d_in[14];
    const float* sen_a = (const float*)d_in[15];
    const float* sen_r = (const float*)d_in[16];
    const float* rel   = (const float*)d_in[17];
    const float* sen_d = (const float*)d_in[18];

    // workspace layout (16B-aligned chunks)
    const long wpk_bytes = 2L * WPK_DIR_BYTES;                 // 359,424
    const long x_bytes   = (long)NT * NS * NI + 1088;          // fp8 + OOB slack
    uchar_t* Wpk  = (uchar_t*)d_ws;
    uchar_t* xbuf = Wpk + wpk_bytes;
    float*   Hbuf = (float*)(xbuf + ((x_bytes + 15) & ~15L));  // 2560*200 f32
    ushort_t* hfb = (ushort_t*)(Hbuf + NS * NH);               // [t][s][NHP] bf16
    ushort_t* hbb = hfb + (long)NT * NS * NHP;

    hipFuncSetAttribute((const void*)gru_kernel,
                        hipFuncAttributeMaxDynamicSharedMemorySize, GRU_LDS_BYTES);

    prep_gather_kernel<<<PREP_BLKS + GATH_BLKS, 256, 0, stream>>>(
        WihF, WhhF, WihB, WhhB, Wpk, tok, p1, p2, emb, pemb, xbuf);
    gru_kernel<<<256, 832, GRU_LDS_BYTES, stream>>>(xbuf, Wpk, bihF, bhhF, bihB, bhhB, hfb, hbb);
    attn_kernel<<<NS, 512, 0, stream>>>(hfb, hbb, aw, Hbuf);
    hipMemsetAsync(d_out, 0, sizeof(float), stream);
    bag_kernel<<<NBAG, 256, 0, stream>>>(Hbuf, label, sen_a, sen_r, rel, sen_d, (float*)d_out);
}